// Round 1
// baseline (981.476 us; speedup 1.0000x reference)
//
#include <hip/hip_runtime.h>

#define NFFT  2048
#define KF    1025          // freq bins per part
#define MROWS 2050          // stacked real+imag W rows
#define TT    513
#define HOPS  512
#define LSIG  262144
#define PADL  1024
#define IMOFF (16 * MROWS * TT)   // offset of imag output tensor

#define BM  128
#define BN  128
#define BK  64
#define LDK 72              // padded LDS row (bf16 elems): 144 B rows -> 16B aligned, 2-way-only bank conflicts

typedef __attribute__((ext_vector_type(8))) short bf16x8;
typedef __attribute__((ext_vector_type(4))) short bf16x4;
typedef __attribute__((ext_vector_type(4))) float f32x4;

// round-to-nearest-even f32 -> bf16 (2 VALU ops; inputs are finite)
__device__ __forceinline__ short f2bf(float f) {
    union { float f; unsigned u; } v; v.f = f;
    unsigned r = v.u + 0x7fffu + ((v.u >> 16) & 1u);
    return (short)(r >> 16);
}

// Main GEMM: t in [0,512), 4 exact N-tiles. 17 M-tiles over 2050 W rows.
__global__ __launch_bounds__(256)
void stft_gemm(const float* __restrict__ x, const float* __restrict__ wr,
               const float* __restrict__ wi, float* __restrict__ out) {
    __shared__ short As[BM * LDK];
    __shared__ short Bs[BN * LDK];

    const int tid   = threadIdx.x;
    const int mBase = blockIdx.x * BM;
    const int t0    = blockIdx.y * BN;
    const int bc    = blockIdx.z;
    const float* xb = x + (size_t)bc * LSIG;

    const int lane = tid & 63;
    const int wid  = tid >> 6;
    const int wm   = (wid >> 1) * 64;   // wave tile origin in M
    const int wn   = (wid & 1) * 64;    // wave tile origin in N
    const int l16  = lane & 15;
    const int quad = lane >> 4;

    const int sr_ = tid >> 4;           // staging row 0..15
    const int sc_ = (tid & 15) * 4;     // staging col (float4 group)

    f32x4 acc[4][4];
#pragma unroll
    for (int i = 0; i < 4; i++)
#pragma unroll
        for (int j = 0; j < 4; j++)
            acc[i][j] = (f32x4){0.f, 0.f, 0.f, 0.f};

    for (int kt = 0; kt < NFFT; kt += BK) {
        __syncthreads();
        // ---- stage A: W rows (real rows 0..1024, imag rows 1025..2049), fp32 -> bf16
#pragma unroll
        for (int i = 0; i < 8; i++) {
            int r  = sr_ + i * 16;
            int gm = mBase + r;
            float4 wv = make_float4(0.f, 0.f, 0.f, 0.f);
            if (gm < MROWS) {
                const float* wp = (gm < KF) ? (wr + (size_t)gm * NFFT)
                                            : (wi + (size_t)(gm - KF) * NFFT);
                wv = *(const float4*)(wp + kt + sc_);
            }
            bf16x4 b4 = { f2bf(wv.x), f2bf(wv.y), f2bf(wv.z), f2bf(wv.w) };
            *(bf16x4*)(&As[r * LDK + sc_]) = b4;
        }
        // ---- stage B: implicit im2col frames with reflect padding
#pragma unroll
        for (int i = 0; i < 8; i++) {
            int f   = sr_ + i * 16;                    // frame idx within tile (t = t0+f < 512)
            int src = (t0 + f) * HOPS - PADL + kt + sc_;
            float4 xv;
            if (src >= 0 && src <= LSIG - 4) {
                xv = *(const float4*)(xb + src);       // 16B aligned: src is a multiple of 4
            } else {
                float tmp[4];
#pragma unroll
                for (int e = 0; e < 4; e++) {
                    int s = src + e;
                    if (s < 0) s = -s;                 // bottom reflect (no edge dup)
                    if (s >= LSIG) s = 2 * LSIG - 2 - s; // top reflect
                    tmp[e] = xb[s];
                }
                xv = make_float4(tmp[0], tmp[1], tmp[2], tmp[3]);
            }
            bf16x4 b4 = { f2bf(xv.x), f2bf(xv.y), f2bf(xv.z), f2bf(xv.w) };
            *(bf16x4*)(&Bs[f * LDK + sc_]) = b4;
        }
        __syncthreads();
        // ---- compute: 2 x 16 MFMA per wave per K-tile
#pragma unroll
        for (int kk = 0; kk < BK; kk += 32) {
            bf16x8 af[4], bfr[4];
#pragma unroll
            for (int i = 0; i < 4; i++)
                af[i] = *(const bf16x8*)(&As[(wm + i * 16 + l16) * LDK + kk + quad * 8]);
#pragma unroll
            for (int j = 0; j < 4; j++)
                bfr[j] = *(const bf16x8*)(&Bs[(wn + j * 16 + l16) * LDK + kk + quad * 8]);
#pragma unroll
            for (int i = 0; i < 4; i++)
#pragma unroll
                for (int j = 0; j < 4; j++)
                    acc[i][j] = __builtin_amdgcn_mfma_f32_16x16x32_bf16(
                        af[i], bfr[j], acc[i][j], 0, 0, 0);
        }
    }

    // ---- epilogue: C/D layout col=lane&15 (t), row=quad*4+reg (W row) [m89-verified]
#pragma unroll
    for (int i = 0; i < 4; i++) {
#pragma unroll
        for (int r = 0; r < 4; r++) {
            int row = mBase + wm + i * 16 + quad * 4 + r;
            if (row >= MROWS) continue;
            float* obase = (row < KF)
                ? (out + (size_t)(bc * KF + row) * TT)
                : (out + IMOFF + (size_t)(bc * KF + (row - KF)) * TT);
            int tcol = t0 + wn + l16;
#pragma unroll
            for (int j = 0; j < 4; j++)
                obase[tcol + j * 16] = acc[i][j][r];
        }
    }
}

// Last column t=512 (reflected tail frame): one wave per (k, bc), fp32 dot.
__global__ __launch_bounds__(64)
void stft_last_col(const float* __restrict__ x, const float* __restrict__ wr,
                   const float* __restrict__ wi, float* __restrict__ out) {
    const int k    = blockIdx.x;    // 0..1024
    const int bc   = blockIdx.y;    // 0..31
    const int lane = threadIdx.x;   // 0..63
    const float* xb = x + (size_t)bc * LSIG;
    float sr = 0.f, si = 0.f;
    for (int n = lane; n < NFFT; n += 64) {
        int src = 512 * HOPS - PADL + n;        // 261120 + n
        if (src >= LSIG) src = 2 * LSIG - 2 - src;
        float xv = xb[src];
        sr += wr[(size_t)k * NFFT + n] * xv;
        si += wi[(size_t)k * NFFT + n] * xv;
    }
#pragma unroll
    for (int off = 32; off; off >>= 1) {
        sr += __shfl_down(sr, off);
        si += __shfl_down(si, off);
    }
    if (lane == 0) {
        out[(size_t)(bc * KF + k) * TT + 512] = sr;
        out[IMOFF + (size_t)(bc * KF + k) * TT + 512] = si;
    }
}

extern "C" void kernel_launch(void* const* d_in, const int* in_sizes, int n_in,
                              void* d_out, int out_size, void* d_ws, size_t ws_size,
                              hipStream_t stream) {
    const float* x  = (const float*)d_in[0];
    const float* wr = (const float*)d_in[1];
    const float* wi = (const float*)d_in[2];
    float* out = (float*)d_out;

    dim3 grid(17, 4, 32);   // M-tiles x N-tiles(t<512) x (b*c)
    stft_gemm<<<grid, 256, 0, stream>>>(x, wr, wi, out);

    dim3 g2(KF, 32);
    stft_last_col<<<g2, 64, 0, stream>>>(x, wr, wi, out);
}

// Round 2
// 371.615 us; speedup vs baseline: 2.6411x; 2.6411x over previous
//
#include <hip/hip_runtime.h>

#define NFFT  2048
#define KF    1025
#define MROWS 2050
#define TT    513
#define HOPS  512
#define LSIG  262144
#define PADL  1024
#define XPADN 264192              // LSIG + 2*PADL
#define IMOFF (16 * MROWS * TT)
#define NBC   32

#define BM  128
#define BN  128
#define BK  64

#define WELEMS (MROWS * NFFT)     // bf16 elems of stacked W

typedef __attribute__((ext_vector_type(8))) short bf16x8;
typedef __attribute__((ext_vector_type(4))) short bf16x4;
typedef __attribute__((ext_vector_type(4))) float f32x4;

__device__ __forceinline__ short f2bf(float f) {
    union { float f; unsigned u; } v; v.f = f;
    unsigned r = v.u + 0x7fffu + ((v.u >> 16) & 1u);
    return (short)(r >> 16);
}
__device__ __forceinline__ float bf2f(short s) {
    union { unsigned u; float f; } v; v.u = ((unsigned)(unsigned short)s) << 16;
    return v.f;
}

typedef __attribute__((address_space(1))) void gas_void;
typedef __attribute__((address_space(3))) void las_void;

__device__ __forceinline__ void gload_lds16(const short* g, short* l) {
    __builtin_amdgcn_global_load_lds((gas_void*)(void*)const_cast<short*>(g),
                                     (las_void*)(void*)l, 16, 0, 0);
}

// ---- prep: W (wr|wi) fp32 -> bf16 contiguous [2050][2048]
__global__ __launch_bounds__(256)
void prep_w(const float* __restrict__ wr, const float* __restrict__ wi,
            short* __restrict__ wbf) {
    const int NG = WELEMS / 4;
    int g = blockIdx.x * 256 + threadIdx.x;
    for (; g < NG; g += gridDim.x * 256) {
        int e = g * 4;
        const float* src = (e < KF * NFFT) ? (wr + e) : (wi + (e - KF * NFFT));
        float4 v = *(const float4*)src;
        bf16x4 b = { f2bf(v.x), f2bf(v.y), f2bf(v.z), f2bf(v.w) };
        *(bf16x4*)(wbf + e) = b;
    }
}

// ---- prep: reflect-padded x -> bf16 [32][264192]
__global__ __launch_bounds__(256)
void prep_x(const float* __restrict__ x, short* __restrict__ xpad) {
    const int bc = blockIdx.y;
    const int j  = (blockIdx.x * 256 + threadIdx.x) * 4;
    const float* xb = x + (size_t)bc * LSIG;
    float4 v;
    if (j >= PADL && j + 4 <= PADL + LSIG) {
        v = *(const float4*)(xb + (j - PADL));
    } else {
        float t[4];
#pragma unroll
        for (int e = 0; e < 4; e++) {
            int s = j + e - PADL;
            if (s < 0) s = -s;
            if (s >= LSIG) s = 2 * LSIG - 2 - s;
            t[e] = xb[s];
        }
        v = make_float4(t[0], t[1], t[2], t[3]);
    }
    bf16x4 b = { f2bf(v.x), f2bf(v.y), f2bf(v.z), f2bf(v.w) };
    *(bf16x4*)(xpad + (size_t)bc * XPADN + j) = b;
}

// ---- main GEMM: t in [0,512). LDS swizzled: chunk (r,c) at r*128B + (c^(r&7))*16B
__global__ __launch_bounds__(256)
void stft_gemm(const short* __restrict__ wbf, const short* __restrict__ xpad,
               float* __restrict__ out) {
    __shared__ short As[BM * BK];
    __shared__ short Bs[BN * BK];

    const int tid   = threadIdx.x;
    const int bc    = blockIdx.x;            // fastest -> W-tile shared across XCD L2
    const int mBase = blockIdx.y * BM;
    const int t0    = blockIdx.z * BN;
    const short* xpb = xpad + (size_t)bc * XPADN;

    const int lane = tid & 63;
    const int wid  = tid >> 6;
    const int wm   = (wid >> 1) * 64;
    const int wn   = (wid & 1) * 64;
    const int l16  = lane & 15;
    const int quad = lane >> 4;

    // staging geometry: each wave DMAs 4 chunks of A and B (8 rows x 128B each)
    const int lrow = lane >> 3;              // row within 8-row chunk
    const int csrc = (lane & 7) ^ lrow;      // source chunk for swizzled slot
    const int rb   = 32 * wid;

    const short* srcA[4]; const short* srcB[4];
    short* dstA[4]; short* dstB[4];
#pragma unroll
    for (int i = 0; i < 4; i++) {
        int r  = rb + 8 * i + lrow;
        int gm = mBase + r; if (gm > MROWS - 1) gm = MROWS - 1;   // clamp: masked at store
        srcA[i] = wbf + (size_t)gm * NFFT + csrc * 8;
        srcB[i] = xpb + (size_t)(t0 + r) * HOPS + csrc * 8;
        dstA[i] = As + (rb + 8 * i) * BK;
        dstB[i] = Bs + (rb + 8 * i) * BK;
    }

    f32x4 acc[4][4];
#pragma unroll
    for (int i = 0; i < 4; i++)
#pragma unroll
        for (int j = 0; j < 4; j++)
            acc[i][j] = (f32x4){0.f, 0.f, 0.f, 0.f};

    const int r7 = l16 & 7;
    for (int kt = 0; kt < NFFT; kt += BK) {
        __syncthreads();
#pragma unroll
        for (int i = 0; i < 4; i++) {
            gload_lds16(srcA[i] + kt, dstA[i]);
            gload_lds16(srcB[i] + kt, dstB[i]);
        }
        __syncthreads();
#pragma unroll
        for (int kk = 0; kk < BK; kk += 32) {
            const int p = ((kk >> 5) * 4 + quad) ^ r7;
            bf16x8 af[4], bfr[4];
#pragma unroll
            for (int i = 0; i < 4; i++)
                af[i] = *(const bf16x8*)(As + (wm + i * 16 + l16) * BK + p * 8);
#pragma unroll
            for (int j = 0; j < 4; j++)
                bfr[j] = *(const bf16x8*)(Bs + (wn + j * 16 + l16) * BK + p * 8);
#pragma unroll
            for (int i = 0; i < 4; i++)
#pragma unroll
                for (int j = 0; j < 4; j++)
                    acc[i][j] = __builtin_amdgcn_mfma_f32_16x16x32_bf16(
                        af[i], bfr[j], acc[i][j], 0, 0, 0);
        }
    }

    // epilogue: C/D layout col=lane&15 (t), row=quad*4+reg
#pragma unroll
    for (int i = 0; i < 4; i++) {
#pragma unroll
        for (int r = 0; r < 4; r++) {
            int row = mBase + wm + i * 16 + quad * 4 + r;
            if (row >= MROWS) continue;
            float* obase = (row < KF)
                ? (out + (size_t)(bc * KF + row) * TT)
                : (out + IMOFF + (size_t)(bc * KF + (row - KF)) * TT);
            int tcol = t0 + wn + l16;
#pragma unroll
            for (int j = 0; j < 4; j++)
                obase[tcol + j * 16] = acc[i][j][r];
        }
    }
}

// ---- t=512 column: out2[m,bc] = sum_n W[m,n]*xpad[bc, 262144+n]. 16 rows/block.
#define LCB 16
__global__ __launch_bounds__(256)
void stft_lastcol(const short* __restrict__ wbf, const short* __restrict__ xpad,
                  float* __restrict__ out) {
    __shared__ float Ws[LCB][136];
    __shared__ float Fs[NBC][132];
    const int tid   = threadIdx.x;
    const int rBase = blockIdx.x * LCB;
    const int row   = tid >> 4;
    const int bcq   = tid & 15;
    const int b0 = bcq * 2, b1 = b0 + 1;

    f32x4 acc0 = {0.f,0.f,0.f,0.f}, acc1 = {0.f,0.f,0.f,0.f};

    for (int kt = 0; kt < NFFT; kt += 128) {
        {   // stage W chunk (16 rows x 128)
            int n  = (tid & 15) * 8;
            int gm = rBase + row; if (gm > MROWS - 1) gm = MROWS - 1;
            bf16x8 v = *(const bf16x8*)(wbf + (size_t)gm * NFFT + kt + n);
#pragma unroll
            for (int e = 0; e < 8; e++) Ws[row][n + e] = bf2f(v[e]);
        }
        {   // stage frames chunk (32 bc x 128)
            int bcf = tid >> 3;
            int n0  = (tid & 7) * 16;
            const short* src = xpad + (size_t)bcf * XPADN + (512 * HOPS) + kt + n0;
            bf16x8 v0 = *(const bf16x8*)src;
            bf16x8 v1 = *(const bf16x8*)(src + 8);
#pragma unroll
            for (int e = 0; e < 8; e++) {
                Fs[bcf][n0 + e]     = bf2f(v0[e]);
                Fs[bcf][n0 + 8 + e] = bf2f(v1[e]);
            }
        }
        __syncthreads();
#pragma unroll 8
        for (int n = 0; n < 128; n += 4) {
            f32x4 w  = *(const f32x4*)&Ws[row][n];
            f32x4 fa = *(const f32x4*)&Fs[b0][n];
            f32x4 fb = *(const f32x4*)&Fs[b1][n];
            acc0 += w * fa;
            acc1 += w * fb;
        }
        __syncthreads();
    }
    int gm = rBase + row;
    if (gm < MROWS) {
        float s0 = acc0[0] + acc0[1] + acc0[2] + acc0[3];
        float s1 = acc1[0] + acc1[1] + acc1[2] + acc1[3];
        size_t o0, o1;
        if (gm < KF) {
            o0 = (size_t)(b0 * KF + gm) * TT + (TT - 1);
            o1 = (size_t)(b1 * KF + gm) * TT + (TT - 1);
        } else {
            o0 = IMOFF + (size_t)(b0 * KF + (gm - KF)) * TT + (TT - 1);
            o1 = IMOFF + (size_t)(b1 * KF + (gm - KF)) * TT + (TT - 1);
        }
        out[o0] = s0;
        out[o1] = s1;
    }
}

extern "C" void kernel_launch(void* const* d_in, const int* in_sizes, int n_in,
                              void* d_out, int out_size, void* d_ws, size_t ws_size,
                              hipStream_t stream) {
    const float* x  = (const float*)d_in[0];
    const float* wr = (const float*)d_in[1];
    const float* wi = (const float*)d_in[2];
    float* out = (float*)d_out;

    short* wbf  = (short*)d_ws;                  // 2050*2048 bf16 = 8.4 MB
    short* xpad = wbf + WELEMS;                  // 32*264192 bf16 = 16.9 MB

    prep_w<<<1025, 256, 0, stream>>>(wr, wi, wbf);
    prep_x<<<dim3(XPADN / 4 / 256, NBC), 256, 0, stream>>>(x, xpad);

    dim3 grid(NBC, 17, 4);   // bc fastest, then M-tiles, then t-tiles
    stft_gemm<<<grid, 256, 0, stream>>>(wbf, xpad, out);

    stft_lastcol<<<(MROWS + LCB - 1) / LCB, 256, 0, stream>>>(wbf, xpad, out);
}

// Round 3
// 353.849 us; speedup vs baseline: 2.7737x; 1.0502x over previous
//
#include <hip/hip_runtime.h>

#define NFFT  2048
#define KF    1025
#define MROWS 2050
#define TT    513
#define HOPS  512
#define LSIG  262144
#define PADL  1024
#define XPADN 264192              // LSIG + 2*PADL
#define IMOFF (16 * MROWS * TT)
#define NBC   32

#define BM  128
#define BN  128
#define BK  64

#define WELEMS (MROWS * NFFT)

typedef __attribute__((ext_vector_type(8))) short bf16x8;
typedef __attribute__((ext_vector_type(4))) short bf16x4;
typedef __attribute__((ext_vector_type(4))) float f32x4;

__device__ __forceinline__ short f2bf(float f) {
    union { float f; unsigned u; } v; v.f = f;
    unsigned r = v.u + 0x7fffu + ((v.u >> 16) & 1u);
    return (short)(r >> 16);
}

typedef __attribute__((address_space(1))) void gas_void;
typedef __attribute__((address_space(3))) void las_void;

__device__ __forceinline__ void gload_lds16(const short* g, short* l) {
    __builtin_amdgcn_global_load_lds((gas_void*)(void*)const_cast<short*>(g),
                                     (las_void*)(void*)l, 16, 0, 0);
}

// ---- fused prep: y<32 -> reflect-padded x slice bc=y; y==32 -> W bf16 convert
__global__ __launch_bounds__(256)
void prep(const float* __restrict__ x, const float* __restrict__ wr,
          const float* __restrict__ wi, short* __restrict__ wbf,
          short* __restrict__ xpad) {
    const int y = blockIdx.y;
    if (y < NBC) {
        const int bc = y;
        const int j  = (blockIdx.x * 256 + threadIdx.x) * 4;   // grid.x=258 -> j<264192
        const float* xb = x + (size_t)bc * LSIG;
        float4 v;
        if (j >= PADL && j + 4 <= PADL + LSIG) {
            v = *(const float4*)(xb + (j - PADL));
        } else {
            float t[4];
#pragma unroll
            for (int e = 0; e < 4; e++) {
                int s = j + e - PADL;
                if (s < 0) s = -s;
                if (s >= LSIG) s = 2 * LSIG - 2 - s;
                t[e] = xb[s];
            }
            v = make_float4(t[0], t[1], t[2], t[3]);
        }
        bf16x4 b = { f2bf(v.x), f2bf(v.y), f2bf(v.z), f2bf(v.w) };
        *(bf16x4*)(xpad + (size_t)bc * XPADN + j) = b;
    } else {
        const int NG = WELEMS / 4;                             // 1,048,576
        int g = blockIdx.x * 256 + threadIdx.x;                // stride 66048
#pragma unroll 4
        for (; g < NG; g += 258 * 256) {
            int e = g * 4;
            const float* src = (e < KF * NFFT) ? (wr + e) : (wi + (e - KF * NFFT));
            float4 v = *(const float4*)src;
            bf16x4 b = { f2bf(v.x), f2bf(v.y), f2bf(v.z), f2bf(v.w) };
            *(bf16x4*)(wbf + e) = b;
        }
    }
}

// ---- main GEMM: rows 0..2047, t in [0,512). LDS swizzle: chunk c at (c^(r&7))*16B
__global__ __launch_bounds__(256)
void stft_gemm(const short* __restrict__ wbf, const short* __restrict__ xpad,
               float* __restrict__ out) {
    __shared__ short As[BM * BK];
    __shared__ short Bs[BN * BK];

    const int tid   = threadIdx.x;
    const int bc    = blockIdx.x;
    const int mBase = blockIdx.y * BM;
    const int t0    = blockIdx.z * BN;
    const short* xpb = xpad + (size_t)bc * XPADN;

    const int lane = tid & 63;
    const int wid  = tid >> 6;
    const int wm   = (wid >> 1) * 64;
    const int wn   = (wid & 1) * 64;
    const int l16  = lane & 15;
    const int quad = lane >> 4;

    const int lrow = lane >> 3;
    const int csrc = (lane & 7) ^ lrow;
    const int rb   = 32 * wid;

    const short* srcA[4]; const short* srcB[4];
    short* dstA[4]; short* dstB[4];
#pragma unroll
    for (int i = 0; i < 4; i++) {
        int r = rb + 8 * i + lrow;
        srcA[i] = wbf + (size_t)(mBase + r) * NFFT + csrc * 8;
        srcB[i] = xpb + (size_t)(t0 + r) * HOPS + csrc * 8;
        dstA[i] = As + (rb + 8 * i) * BK;
        dstB[i] = Bs + (rb + 8 * i) * BK;
    }

    f32x4 acc[4][4];
#pragma unroll
    for (int i = 0; i < 4; i++)
#pragma unroll
        for (int j = 0; j < 4; j++)
            acc[i][j] = (f32x4){0.f, 0.f, 0.f, 0.f};

    const int r7 = l16 & 7;
    for (int kt = 0; kt < NFFT; kt += BK) {
        __syncthreads();
#pragma unroll
        for (int i = 0; i < 4; i++) {
            gload_lds16(srcA[i] + kt, dstA[i]);
            gload_lds16(srcB[i] + kt, dstB[i]);
        }
        __syncthreads();
#pragma unroll
        for (int kk = 0; kk < BK; kk += 32) {
            const int p = ((kk >> 5) * 4 + quad) ^ r7;
            bf16x8 af[4], bfr[4];
#pragma unroll
            for (int i = 0; i < 4; i++)
                af[i] = *(const bf16x8*)(As + (wm + i * 16 + l16) * BK + p * 8);
#pragma unroll
            for (int j = 0; j < 4; j++)
                bfr[j] = *(const bf16x8*)(Bs + (wn + j * 16 + l16) * BK + p * 8);
#pragma unroll
            for (int i = 0; i < 4; i++)
#pragma unroll
                for (int j = 0; j < 4; j++)
                    acc[i][j] = __builtin_amdgcn_mfma_f32_16x16x32_bf16(
                        af[i], bfr[j], acc[i][j], 0, 0, 0);
        }
    }

#pragma unroll
    for (int i = 0; i < 4; i++) {
#pragma unroll
        for (int r = 0; r < 4; r++) {
            int row = mBase + wm + i * 16 + quad * 4 + r;     // always < 2048
            float* obase = (row < KF)
                ? (out + (size_t)(bc * KF + row) * TT)
                : (out + IMOFF + (size_t)(bc * KF + (row - KF)) * TT);
            int tcol = t0 + wn + l16;
#pragma unroll
            for (int j = 0; j < 4; j++)
                obase[tcol + j * 16] = acc[i][j][r];
        }
    }
}

// ---- tail: blocks 0..15  = t=512 column for rows 0..2047 (M=2048,N=32bc,K=2048)
//            blocks 16..303 = imag rows 1023/1024 (W rows 2048/2049) for all t,bc
__global__ __launch_bounds__(256)
void stft_tail(const short* __restrict__ wbf, const short* __restrict__ xpad,
               float* __restrict__ out) {
    const int bx   = blockIdx.x;
    const int tid  = threadIdx.x;
    const int lane = tid & 63;
    const int wid  = tid >> 6;
    const int l16  = lane & 15;
    const int quad = lane >> 4;

    if (bx < 16) {
        const int mBase = bx * 128 + wid * 32;
        f32x4 acc[2][2];
#pragma unroll
        for (int i = 0; i < 2; i++)
#pragma unroll
            for (int j = 0; j < 2; j++) acc[i][j] = (f32x4){0.f,0.f,0.f,0.f};
        const short* a0p = wbf + (size_t)(mBase + l16) * NFFT + quad * 8;
        const short* a1p = a0p + (size_t)16 * NFFT;
        const short* b0p = xpad + (size_t)l16 * XPADN + LSIG + quad * 8;       // tail frame start = 512*HOP
        const short* b1p = b0p + (size_t)16 * XPADN;
        for (int kt = 0; kt < NFFT; kt += 32) {
            bf16x8 a0 = *(const bf16x8*)(a0p + kt);
            bf16x8 a1 = *(const bf16x8*)(a1p + kt);
            bf16x8 b0 = *(const bf16x8*)(b0p + kt);
            bf16x8 b1 = *(const bf16x8*)(b1p + kt);
            acc[0][0] = __builtin_amdgcn_mfma_f32_16x16x32_bf16(a0, b0, acc[0][0], 0,0,0);
            acc[0][1] = __builtin_amdgcn_mfma_f32_16x16x32_bf16(a0, b1, acc[0][1], 0,0,0);
            acc[1][0] = __builtin_amdgcn_mfma_f32_16x16x32_bf16(a1, b0, acc[1][0], 0,0,0);
            acc[1][1] = __builtin_amdgcn_mfma_f32_16x16x32_bf16(a1, b1, acc[1][1], 0,0,0);
        }
#pragma unroll
        for (int i = 0; i < 2; i++)
#pragma unroll
            for (int j = 0; j < 2; j++)
#pragma unroll
                for (int r = 0; r < 4; r++) {
                    int row = mBase + i * 16 + quad * 4 + r;
                    int bc  = j * 16 + l16;
                    size_t o = (row < KF)
                        ? ((size_t)(bc * KF + row) * TT + (TT - 1))
                        : (IMOFF + (size_t)(bc * KF + (row - KF)) * TT + (TT - 1));
                    out[o] = acc[i][j][r];
                }
    } else {
        const int idx   = bx - 16;            // 0..287
        const int bc    = idx / 9;
        const int tb    = idx % 9;
        const int ttile = tb * 4 + wid;       // 0..35
        if (ttile >= 33) return;
        const int t0  = ttile * 16;
        const int tcl = min(t0 + l16, 512);
        const int wrow = 2048 + min(l16, 1);
        const short* ap = xpad + (size_t)bc * XPADN + (size_t)tcl * HOPS + quad * 8;
        const short* bp = wbf + (size_t)wrow * NFFT + quad * 8;
        f32x4 acc0 = {0.f,0.f,0.f,0.f}, acc1 = {0.f,0.f,0.f,0.f};
        for (int kt = 0; kt < NFFT; kt += 64) {
            bf16x8 a0 = *(const bf16x8*)(ap + kt);
            bf16x8 b0 = *(const bf16x8*)(bp + kt);
            bf16x8 a1 = *(const bf16x8*)(ap + kt + 32);
            bf16x8 b1 = *(const bf16x8*)(bp + kt + 32);
            acc0 = __builtin_amdgcn_mfma_f32_16x16x32_bf16(a0, b0, acc0, 0,0,0);
            acc1 = __builtin_amdgcn_mfma_f32_16x16x32_bf16(a1, b1, acc1, 0,0,0);
        }
        if (l16 < 2) {
            size_t base = IMOFF + (size_t)(bc * KF + 1023 + l16) * TT;
#pragma unroll
            for (int r = 0; r < 4; r++) {
                int t = t0 + quad * 4 + r;
                if (t < TT) out[base + t] = acc0[r] + acc1[r];
            }
        }
    }
}

extern "C" void kernel_launch(void* const* d_in, const int* in_sizes, int n_in,
                              void* d_out, int out_size, void* d_ws, size_t ws_size,
                              hipStream_t stream) {
    const float* x  = (const float*)d_in[0];
    const float* wr = (const float*)d_in[1];
    const float* wi = (const float*)d_in[2];
    float* out = (float*)d_out;

    short* wbf  = (short*)d_ws;                  // 2050*2048 bf16
    short* xpad = wbf + WELEMS;                  // 32*264192 bf16

    prep<<<dim3(258, NBC + 1), 256, 0, stream>>>(x, wr, wi, wbf, xpad);

    dim3 grid(NBC, 16, 4);
    stft_gemm<<<grid, 256, 0, stream>>>(wbf, xpad, out);

    stft_tail<<<304, 256, 0, stream>>>(wbf, xpad, out);
}

// Round 4
// 319.253 us; speedup vs baseline: 3.0743x; 1.1084x over previous
//
#include <hip/hip_runtime.h>
#include <hip/hip_fp16.h>

#define NFFT  2048
#define KF    1025
#define MROWS 2050
#define TT    513
#define HOPS  512
#define LSIG  262144
#define PADL  1024
#define XPADN 264192              // LSIG + 2*PADL
#define XDN   66048               // XPADN / 4 (deinterleaved plane length)
#define IMOFF (16 * MROWS * TT)
#define NBC   32

typedef __attribute__((ext_vector_type(8))) short bf16x8;
typedef __attribute__((ext_vector_type(4))) short bf16x4;
typedef __attribute__((ext_vector_type(4))) float f32x4;

__device__ __forceinline__ short f2bf(float f) {
    union { float f; unsigned u; } v; v.f = f;
    unsigned r = v.u + 0x7fffu + ((v.u >> 16) & 1u);
    return (short)(r >> 16);
}

typedef __attribute__((address_space(1))) void gas_void;
typedef __attribute__((address_space(3))) void las_void;

__device__ __forceinline__ void gload_lds16(const short* g, short* l) {
    __builtin_amdgcn_global_load_lds((gas_void*)(void*)const_cast<short*>(g),
                                     (las_void*)(void*)l, 16, 0, 0);
}

// ---- prep: reflect-padded x -> bf16 xpad[32][264192] AND deinterleaved xd[4][32][66048]
__global__ __launch_bounds__(256)
void prep_x(const float* __restrict__ x, short* __restrict__ xpad,
            short* __restrict__ xd) {
    const int bc = blockIdx.y;
    const int j4 = (blockIdx.x * 256 + threadIdx.x) * 4;   // 258*256*4 = 264192 exact
    const float* xb = x + (size_t)bc * LSIG;
    float4 v;
    if (j4 >= PADL && j4 + 4 <= PADL + LSIG) {
        v = *(const float4*)(xb + (j4 - PADL));
    } else {
        float t[4];
#pragma unroll
        for (int e = 0; e < 4; e++) {
            int s = j4 + e - PADL;
            if (s < 0) s = -s;
            if (s >= LSIG) s = 2 * LSIG - 2 - s;
            t[e] = xb[s];
        }
        v = make_float4(t[0], t[1], t[2], t[3]);
    }
    bf16x4 b = { f2bf(v.x), f2bf(v.y), f2bf(v.z), f2bf(v.w) };
    *(bf16x4*)(xpad + (size_t)bc * XPADN + j4) = b;
    const int j = j4 >> 2;                                 // n = 4j + r
#pragma unroll
    for (int r = 0; r < 4; r++)
        xd[((size_t)r * NBC + bc) * XDN + j] = b[r];
}

// ---- prep: radix-4 basis A[r][row=2*kap+reim][m], 4 x 512 x 512 bf16
// A_re[kap,m] = win[4m+r]*cos(2*pi*kap*m/512); A_im = -win[4m+r]*sin(...)
__global__ __launch_bounds__(256)
void prep_basis(short* __restrict__ A) {
    const int r    = blockIdx.y;
    const int row  = blockIdx.x;          // 0..511
    const int kap  = row >> 1;
    const int reim = row & 1;
    for (int m = threadIdx.x; m < 512; m += 256) {
        float sv, cv;
        sincospif((float)(kap * m) * (1.0f / 256.0f), &sv, &cv);
        float win = 0.5f - 0.5f * cospif((float)(4 * m + r) * (1.0f / 1024.0f));
        float val = reim ? (-win * sv) : (win * cv);
        A[((size_t)r * 512 + row) * 512 + m] = f2bf(val);
    }
}

// ---- radix-4 sub-DFT GEMM: S[bcl][r][row:512][t:512] fp16, K=512
__global__ __launch_bounds__(256)
void stft_gemm_s(const short* __restrict__ Ab, const short* __restrict__ xd,
                 __half* __restrict__ S, int bc0) {
    __shared__ short As[128 * 64];
    __shared__ short Bs[128 * 64];

    const int tid   = threadIdx.x;
    const int bcl   = blockIdx.x;
    const int r     = blockIdx.y >> 2;
    const int mBase = (blockIdx.y & 3) * 128;
    const int t0    = blockIdx.z * 128;
    const short* Ap  = Ab + (size_t)r * 512 * 512;
    const short* xdp = xd + ((size_t)r * NBC + (bc0 + bcl)) * XDN;

    const int lane = tid & 63;
    const int wid  = tid >> 6;
    const int wm   = (wid >> 1) * 64;
    const int wn   = (wid & 1) * 64;
    const int l16  = lane & 15;
    const int quad = lane >> 4;

    const int lrow = lane >> 3;
    const int csrc = (lane & 7) ^ lrow;
    const int rb   = 32 * wid;

    const short* srcA[4]; const short* srcB[4];
    short* dstA[4]; short* dstB[4];
#pragma unroll
    for (int i = 0; i < 4; i++) {
        int rr = rb + 8 * i + lrow;
        srcA[i] = Ap  + (size_t)(mBase + rr) * 512 + csrc * 8;
        srcB[i] = xdp + (size_t)(t0 + rr) * 128 + csrc * 8;   // hop' = 128
        dstA[i] = As + (rb + 8 * i) * 64;
        dstB[i] = Bs + (rb + 8 * i) * 64;
    }

    f32x4 acc[4][4];
#pragma unroll
    for (int i = 0; i < 4; i++)
#pragma unroll
        for (int j = 0; j < 4; j++)
            acc[i][j] = (f32x4){0.f, 0.f, 0.f, 0.f};

    const int r7 = l16 & 7;
    for (int kt = 0; kt < 512; kt += 64) {
        __syncthreads();
#pragma unroll
        for (int i = 0; i < 4; i++) {
            gload_lds16(srcA[i] + kt, dstA[i]);
            gload_lds16(srcB[i] + kt, dstB[i]);
        }
        __syncthreads();
#pragma unroll
        for (int kk = 0; kk < 64; kk += 32) {
            const int p = ((kk >> 5) * 4 + quad) ^ r7;
            bf16x8 af[4], bfr[4];
#pragma unroll
            for (int i = 0; i < 4; i++)
                af[i] = *(const bf16x8*)(As + (wm + i * 16 + l16) * 64 + p * 8);
#pragma unroll
            for (int j = 0; j < 4; j++)
                bfr[j] = *(const bf16x8*)(Bs + (wn + j * 16 + l16) * 64 + p * 8);
#pragma unroll
            for (int i = 0; i < 4; i++)
#pragma unroll
                for (int j = 0; j < 4; j++)
                    acc[i][j] = __builtin_amdgcn_mfma_f32_16x16x32_bf16(
                        af[i], bfr[j], acc[i][j], 0, 0, 0);
        }
    }

    __half* Sb = S + ((size_t)bcl * 4 + r) * (512 * 512);
#pragma unroll
    for (int i = 0; i < 4; i++) {
#pragma unroll
        for (int rr = 0; rr < 4; rr++) {
            int row = mBase + wm + i * 16 + quad * 4 + rr;
            int tc  = t0 + wn + l16;
#pragma unroll
            for (int j = 0; j < 4; j++)
                Sb[(size_t)row * 512 + tc + j * 16] = __float2half(acc[i][j][rr]);
        }
    }
}

// ---- combine: Y[k] = sum_r tw_r * S_r[k mod 512]; covers all k except {256,768}, t<512
__global__ __launch_bounds__(256)
void stft_combine(const __half* __restrict__ S, float* __restrict__ out, int bc0) {
    const int kap = blockIdx.x;          // 0..255
    const int bcl = blockIdx.y;
    const int bcg = bc0 + bcl;
    float s1, c1;
    sincospif((float)kap * (1.0f / 1024.0f), &s1, &c1);
    const float cr1 = c1,               ci1 = -s1;
    const float cr2 = cr1*cr1 - ci1*ci1, ci2 = 2.f*cr1*ci1;
    const float cr3 = cr2*cr1 - ci2*ci1, ci3 = cr2*ci1 + ci2*cr1;
    const __half* Sb = S + (size_t)bcl * 4 * 512 * 512;
    float* oRe = out + (size_t)bcg * KF * TT;
    float* oIm = out + IMOFF + (size_t)bcg * KF * TT;

#pragma unroll
    for (int ti = 0; ti < 2; ti++) {
        const int t = threadIdx.x + ti * 256;
        float a[4], b[4];
#pragma unroll
        for (int r = 0; r < 4; r++) {
            a[r] = __half2float(Sb[((size_t)r * 512 + 2 * kap) * 512 + t]);
            b[r] = __half2float(Sb[((size_t)r * 512 + 2 * kap + 1) * 512 + t]);
        }
        const float u0 = a[0], v0 = b[0];
        const float u1 = cr1*a[1] - ci1*b[1], v1 = cr1*b[1] + ci1*a[1];
        const float u2 = cr2*a[2] - ci2*b[2], v2 = cr2*b[2] + ci2*a[2];
        const float u3 = cr3*a[3] - ci3*b[3], v3 = cr3*b[3] + ci3*a[3];
        oRe[(size_t)kap * TT + t]          = u0 + u1 + u2 + u3;
        oIm[(size_t)kap * TT + t]          = v0 + v1 + v2 + v3;
        oRe[(size_t)(kap + 512) * TT + t]  = u0 + v1 - u2 - v3;
        oIm[(size_t)(kap + 512) * TT + t]  = v0 - u1 - v2 + u3;
        oRe[(size_t)(512 - kap) * TT + t]  = u0 - v1 - u2 + v3;
        oIm[(size_t)(512 - kap) * TT + t]  = -(v0 + u1 - v2 - u3);
        oRe[(size_t)(1024 - kap) * TT + t] = u0 - u1 + u2 - u3;
        oIm[(size_t)(1024 - kap) * TT + t] = -(v0 - v1 + v2 - v3);
    }
}

// ---- tail: blocks 0..16  = t=512 column, all 2050 W rows (fp32 W direct)
//            blocks 17..272 = k in {256,768} re/im, t in [0,512)
__global__ __launch_bounds__(256)
void stft_tail(const float* __restrict__ wr, const float* __restrict__ wi,
               const short* __restrict__ xpad, float* __restrict__ out) {
    const int bx   = blockIdx.x;
    const int tid  = threadIdx.x;
    const int lane = tid & 63;
    const int wid  = tid >> 6;
    const int l16  = lane & 15;
    const int quad = lane >> 4;

    if (bx < 17) {
        const int mBase = bx * 128 + wid * 32;
        f32x4 acc[2][2];
#pragma unroll
        for (int i = 0; i < 2; i++)
#pragma unroll
            for (int j = 0; j < 2; j++) acc[i][j] = (f32x4){0.f,0.f,0.f,0.f};
        int ra0 = min(mBase + l16, MROWS - 1);
        int ra1 = min(mBase + 16 + l16, MROWS - 1);
        const float* a0p = ((ra0 < KF) ? (wr + (size_t)ra0 * NFFT)
                                       : (wi + (size_t)(ra0 - KF) * NFFT)) + quad * 8;
        const float* a1p = ((ra1 < KF) ? (wr + (size_t)ra1 * NFFT)
                                       : (wi + (size_t)(ra1 - KF) * NFFT)) + quad * 8;
        const short* b0p = xpad + (size_t)l16 * XPADN + LSIG + quad * 8;  // tail frame @512*HOP
        const short* b1p = b0p + (size_t)16 * XPADN;
        for (int kt = 0; kt < NFFT; kt += 32) {
            float4 f0 = *(const float4*)(a0p + kt), f1 = *(const float4*)(a0p + kt + 4);
            float4 g0 = *(const float4*)(a1p + kt), g1 = *(const float4*)(a1p + kt + 4);
            bf16x8 a0 = { f2bf(f0.x), f2bf(f0.y), f2bf(f0.z), f2bf(f0.w),
                          f2bf(f1.x), f2bf(f1.y), f2bf(f1.z), f2bf(f1.w) };
            bf16x8 a1 = { f2bf(g0.x), f2bf(g0.y), f2bf(g0.z), f2bf(g0.w),
                          f2bf(g1.x), f2bf(g1.y), f2bf(g1.z), f2bf(g1.w) };
            bf16x8 b0 = *(const bf16x8*)(b0p + kt);
            bf16x8 b1 = *(const bf16x8*)(b1p + kt);
            acc[0][0] = __builtin_amdgcn_mfma_f32_16x16x32_bf16(a0, b0, acc[0][0], 0,0,0);
            acc[0][1] = __builtin_amdgcn_mfma_f32_16x16x32_bf16(a0, b1, acc[0][1], 0,0,0);
            acc[1][0] = __builtin_amdgcn_mfma_f32_16x16x32_bf16(a1, b0, acc[1][0], 0,0,0);
            acc[1][1] = __builtin_amdgcn_mfma_f32_16x16x32_bf16(a1, b1, acc[1][1], 0,0,0);
        }
#pragma unroll
        for (int i = 0; i < 2; i++)
#pragma unroll
            for (int j = 0; j < 2; j++)
#pragma unroll
                for (int rr = 0; rr < 4; rr++) {
                    int row = mBase + i * 16 + quad * 4 + rr;
                    if (row >= MROWS) continue;
                    int bc = j * 16 + l16;
                    size_t o = (row < KF)
                        ? ((size_t)(bc * KF + row) * TT + (TT - 1))
                        : (IMOFF + (size_t)(bc * KF + (row - KF)) * TT + (TT - 1));
                    out[o] = acc[i][j][rr];
                }
    } else {
        const int idx = bx - 17;             // 0..255
        const int bc  = idx >> 3;
        const int tb  = idx & 7;
        const int t0  = (tb * 4 + wid) * 16; // 0..496
        const int ls  = l16 & 3;
        const int k   = 256 + (ls & 1) * 512;
        const float* bp = ((ls & 2) ? wi : wr) + (size_t)k * NFFT + quad * 8;
        const short* ap = xpad + (size_t)bc * XPADN + (size_t)(t0 + l16) * HOPS + quad * 8;
        f32x4 acc0 = {0.f,0.f,0.f,0.f}, acc1 = {0.f,0.f,0.f,0.f};
        for (int kt = 0; kt < NFFT; kt += 64) {
            bf16x8 a0 = *(const bf16x8*)(ap + kt);
            bf16x8 a1 = *(const bf16x8*)(ap + kt + 32);
            float4 f0 = *(const float4*)(bp + kt), f1 = *(const float4*)(bp + kt + 4);
            float4 g0 = *(const float4*)(bp + kt + 32), g1 = *(const float4*)(bp + kt + 36);
            bf16x8 b0 = { f2bf(f0.x), f2bf(f0.y), f2bf(f0.z), f2bf(f0.w),
                          f2bf(f1.x), f2bf(f1.y), f2bf(f1.z), f2bf(f1.w) };
            bf16x8 b1 = { f2bf(g0.x), f2bf(g0.y), f2bf(g0.z), f2bf(g0.w),
                          f2bf(g1.x), f2bf(g1.y), f2bf(g1.z), f2bf(g1.w) };
            acc0 = __builtin_amdgcn_mfma_f32_16x16x32_bf16(a0, b0, acc0, 0,0,0);
            acc1 = __builtin_amdgcn_mfma_f32_16x16x32_bf16(a1, b1, acc1, 0,0,0);
        }
        if (l16 < 4) {
            size_t base = ((ls & 2) ? (size_t)IMOFF : 0) + (size_t)(bc * KF + k) * TT;
#pragma unroll
            for (int rr = 0; rr < 4; rr++) {
                int t = t0 + quad * 4 + rr;          // <= 511
                out[base + t] = acc0[rr] + acc1[rr];
            }
        }
    }
}

extern "C" void kernel_launch(void* const* d_in, const int* in_sizes, int n_in,
                              void* d_out, int out_size, void* d_ws, size_t ws_size,
                              hipStream_t stream) {
    const float* x  = (const float*)d_in[0];
    const float* wr = (const float*)d_in[1];
    const float* wi = (const float*)d_in[2];
    float* out = (float*)d_out;

    char* ws = (char*)d_ws;
    short*  xpad = (short*)ws;                                  // 16,908,288 B
    short*  xd   = (short*)(ws + 16908288);                     // 16,908,288 B
    short*  Ab   = (short*)(ws + 33816576);                     //  2,097,152 B
    __half* S    = (__half*)(ws + 35913728);                    //  CH * 2,097,152 B

    const long long s_per_bc = 4LL * 512 * 512 * sizeof(__half);
    long long avail = (long long)ws_size - 35913728LL;
    int CH = (int)(avail / s_per_bc);
    if (CH < 1) CH = 1;
    if (CH > NBC) CH = NBC;

    prep_x<<<dim3(258, NBC), 256, 0, stream>>>(x, xpad, xd);
    prep_basis<<<dim3(512, 4), 256, 0, stream>>>(Ab);

    for (int bc0 = 0; bc0 < NBC; bc0 += CH) {
        int c = NBC - bc0 < CH ? NBC - bc0 : CH;
        stft_gemm_s<<<dim3(c, 16, 4), 256, 0, stream>>>(Ab, xd, S, bc0);
        stft_combine<<<dim3(256, c), 256, 0, stream>>>(S, out, bc0);
    }

    stft_tail<<<17 + 256, 256, 0, stream>>>(wr, wi, xpad, out);
}